// Round 5
// baseline (290.300 us; speedup 1.0000x reference)
//
#include <hip/hip_runtime.h>
#include <hip/hip_cooperative_groups.h>

namespace cg = cooperative_groups;

#define A_N 131072
#define B_N 8
#define G_N 64
#define C_INTN 8
#define EPSF 1e-6f

#define NBLK 512
#define NTHR 256

// spatial binning: anchors in [0,200]^2, max (w_a+w_g)/2 separation ~7 < 8 = cell
#define NCELL 25
#define NCC (NCELL * NCELL)
#define CAP 1024
#define INV_CELL 0.125f
#define CNT_STRIDE 16      // one counter per 64B cache line (atomic contention fix)

// u32 packed key: top 26 bits of fmono(iou) | (63-g). fmono(x>=0) = bits|0x80000000.
#define KEY_INIT 0x8000003Fu   // iou = 0.0, g = 0
#define KEY_POS  0xBF199980u   // trunc26(fmono(0.6f));  0.6f  = 0x3F19999A
#define KEY_NEG  0xBEE66640u   // trunc26(fmono(0.45f)); 0.45f = 0x3EE66666

// ---------- helpers ----------

__device__ __forceinline__ unsigned long long shfl_xor_u64(unsigned long long v, int m) {
    unsigned int lo = (unsigned int)(v & 0xFFFFFFFFull);
    unsigned int hi = (unsigned int)(v >> 32);
    lo = __shfl_xor(lo, m, 64);
    hi = __shfl_xor(hi, m, 64);
    return ((unsigned long long)hi << 32) | lo;
}

__device__ __forceinline__ float focal_term(float xl, bool pos) {
    float z = pos ? -xl : xl;
    float ce = fmaxf(z, 0.f) + log1pf(expf(-fabsf(z)));  // softplus(z)
    float p = 1.f / (1.f + expf(-xl));
    float omp = pos ? (1.f - p) : p;                     // 1 - p_t
    return (pos ? 0.25f : 0.75f) * ce * omp * omp;
}

// box smooth-L1 + intention CE for a positive anchor (ap: anchor row, m: gt row,
// bp: box_preds row, il: intention logits row, it: gt intention class)
__device__ __forceinline__ void pos_losses(const float* ap, const float* m,
                                           const float* bp, const float* il,
                                           int it, float& lb, float& li) {
    float ax = ap[0], ay = ap[1];
    float aw = ap[2] + EPSF, al = ap[3] + EPSF, aang = ap[4];
    float hd = m[4] - aang;
    float bt[6];
    bt[0] = (m[0] - ax) / aw;
    bt[1] = (m[1] - ay) / al;
    bt[2] = logf(m[2] / aw + EPSF);
    bt[3] = logf(m[3] / al + EPSF);
    bt[4] = sinf(hd);
    bt[5] = cosf(hd);
    lb = 0.f;
#pragma unroll
    for (int k = 0; k < 6; ++k) {
        float d = fabsf(bp[k] - bt[k]);
        lb += (d < (1.0f / 9.0f)) ? (4.5f * d * d) : (d - 0.5f / 9.0f);
    }
    float lv[C_INTN];
#pragma unroll
    for (int c = 0; c < C_INTN; ++c) lv[c] = il[c];
    float mx = lv[0];
#pragma unroll
    for (int c = 1; c < C_INTN; ++c) mx = fmaxf(mx, lv[c]);
    float s = 0.f;
#pragma unroll
    for (int c = 0; c < C_INTN; ++c) s += expf(lv[c] - mx);
    float sel = lv[0];
#pragma unroll
    for (int c = 1; c < C_INTN; ++c) sel = (c == it) ? lv[c] : sel;  // static-index select
    li = (mx + logf(s)) - sel;
}

// ---------- the fused cooperative kernel ----------

__global__ void __launch_bounds__(NTHR, 2) k_fused(
    const float* __restrict__ anchors, const float* __restrict__ gt_boxes,
    const int* __restrict__ gt_valid, const int* __restrict__ gt_int,
    const float* __restrict__ cls_logits, const float* __restrict__ box_preds,
    const float* __restrict__ int_logits,
    float4* __restrict__ prep4, float* __restrict__ prepA,
    unsigned int* __restrict__ packed, int* __restrict__ cell_count,
    int* __restrict__ cell_list, int* __restrict__ forced_pair,
    float* __restrict__ partials, float* __restrict__ out)
{
    cg::grid_group grid = cg::this_grid();
    const int tid = threadIdx.x;
    const int blk = blockIdx.x;
    const int gtid = blk * NTHR + tid;   // == anchor index (NBLK*NTHR == A_N)

    __shared__ float s_gb[G_N * 5];
    __shared__ int   s_gi[G_N];
    __shared__ unsigned long long s_u64[4];
    __shared__ float s_red[4][4];

    // ---- phase A: zero counters + anchor prep + packed init ----
    if (gtid < NCC * CNT_STRIDE) cell_count[gtid] = 0;
    const int a = gtid;
    const float* ap = anchors + a * 5;
    float x = ap[0], y = ap[1], w = ap[2], l = ap[3];
    prep4[a] = make_float4(x - w * 0.5f, x + w * 0.5f, y - l * 0.5f, y + l * 0.5f);
    prepA[a] = w * l + EPSF;   // area_a + EPS
#pragma unroll
    for (int b = 0; b < B_N; ++b) packed[b * A_N + a] = KEY_INIT;

    grid.sync();

    // ---- phase B: spatial binning (counters are now zeroed grid-wide) ----
    {
        int icx = min(max((int)(x * INV_CELL), 0), NCELL - 1);
        int icy = min(max((int)(y * INV_CELL), 0), NCELL - 1);
        int cc = icy * NCELL + icx;
        int slot = atomicAdd(&cell_count[cc * CNT_STRIDE], 1);   // 625 independent lines
        if (slot < CAP) cell_list[cc * CAP + slot] = a;
    }

    grid.sync();

    // ---- phase C: per-(b,g) neighborhood scan; argmax-over-g scatter + best-anchor reduce ----
    {
        const int g = blk & (G_N - 1);
        const int b = blk >> 6;
        unsigned long long best = 0ull;
        if (gt_valid[b * G_N + g] > 0) {
            const float* gb = gt_boxes + (b * G_N + g) * 5;
            float gx = gb[0], gy = gb[1], gw = gb[2], gl = gb[3];
            float gx1 = gx - gw * 0.5f, gx2 = gx + gw * 0.5f;
            float gy1 = gy - gl * 0.5f, gy2 = gy + gl * 0.5f;
            float ag = gw * gl;
            int ccx = (int)floorf(gx * INV_CELL);
            int ccy = (int)floorf(gy * INV_CELL);
            int x0 = max(ccx - 1, 0), x1 = min(ccx + 1, NCELL - 1);
            int y0 = max(ccy - 1, 0), y1 = min(ccy + 1, NCELL - 1);
            unsigned int glow = (unsigned int)(63 - g);

            for (int cy = y0; cy <= y1; ++cy) {
                for (int cx = x0; cx <= x1; ++cx) {
                    int cc = cy * NCELL + cx;
                    int cnt = min(cell_count[cc * CNT_STRIDE], CAP);
                    for (int i = tid; i < cnt; i += NTHR) {
                        int aa = cell_list[cc * CAP + i];
                        float4 p = prep4[aa];
                        float areaa = prepA[aa];
                        float iw = fmaxf(fminf(p.y, gx2) - fmaxf(p.x, gx1), 0.0f);
                        float ih = fmaxf(fminf(p.w, gy2) - fmaxf(p.z, gy1), 0.0f);
                        float inter = iw * ih;
                        if (inter > 0.0f) {
                            float iou = inter * __builtin_amdgcn_rcpf(areaa + ag - inter);
                            unsigned int fm = __float_as_uint(iou) | 0x80000000u; // fmono, iou>0
                            atomicMax(&packed[b * A_N + aa], (fm & 0xFFFFFFC0u) | glow);
                            unsigned long long key = ((unsigned long long)fm << 32) |
                                                     (unsigned long long)(~(unsigned int)aa);
                            if (key > best) best = key;  // exact iou; tie -> smaller a
                        }
                    }
                }
            }
        }
#pragma unroll
        for (int msk = 1; msk < 64; msk <<= 1) {
            unsigned long long o = shfl_xor_u64(best, msk);
            if (o > best) best = o;
        }
        int lane = tid & 63, wv = tid >> 6;
        if (lane == 0) s_u64[wv] = best;
        __syncthreads();
        if (tid == 0) {
            for (int w2 = 1; w2 < 4; ++w2) if (s_u64[w2] > best) best = s_u64[w2];
            int outa = -1;
            if (best != 0ull) {
                float biou = __uint_as_float((unsigned int)(best >> 32) & 0x7FFFFFFFu);
                int aa = (int)(~(unsigned int)(best & 0xFFFFFFFFull));
                if (biou >= 0.45f) outa = aa;
            }
            forced_pair[b * G_N + g] = outa;
        }
    }

    grid.sync();

    // ---- phase D: dense loss over unforced labels -> per-block partials ----
    {
        const int b = blk >> 6, chunk = blk & 63;
        if (tid < G_N) {
#pragma unroll
            for (int k = 0; k < 5; ++k) s_gb[tid * 5 + k] = gt_boxes[(b * G_N + tid) * 5 + k];
            s_gi[tid] = gt_int[b * G_N + tid];
        }
        __syncthreads();

        const int a_base = chunk * 2048 + tid * 8;   // 8 consecutive anchors/thread
        const long ba = (long)b * A_N + a_base;

        uint4  k4a = *reinterpret_cast<const uint4*>(packed + ba);
        uint4  k4b = *reinterpret_cast<const uint4*>(packed + ba + 4);
        float4 xla = *reinterpret_cast<const float4*>(cls_logits + ba);
        float4 xlb = *reinterpret_cast<const float4*>(cls_logits + ba + 4);

        unsigned int keys[8] = {k4a.x, k4a.y, k4a.z, k4a.w, k4b.x, k4b.y, k4b.z, k4b.w};
        float xls[8] = {xla.x, xla.y, xla.z, xla.w, xlb.x, xlb.y, xlb.z, xlb.w};

        float acc_f = 0.f, acc_b = 0.f, acc_i = 0.f, acc_p = 0.f;
#pragma unroll
        for (int i = 0; i < 8; ++i) {
            unsigned int key = keys[i];
            bool pos = key >= KEY_POS;
            bool neg = key < KEY_NEG;
            if (pos | neg) acc_f += focal_term(xls[i], pos);
            if (pos) {
                acc_p += 1.f;
                int g = 63 - (int)(key & 63u);
                int aa = a_base + i;
                long baa = (long)b * A_N + aa;
                float lb, li;
                pos_losses(anchors + aa * 5, s_gb + g * 5,
                           box_preds + baa * 6, int_logits + baa * C_INTN,
                           s_gi[g], lb, li);
                acc_b += lb; acc_i += li;
            }
        }

#pragma unroll
        for (int msk = 1; msk < 64; msk <<= 1) {
            acc_f += __shfl_xor(acc_f, msk, 64);
            acc_b += __shfl_xor(acc_b, msk, 64);
            acc_i += __shfl_xor(acc_i, msk, 64);
            acc_p += __shfl_xor(acc_p, msk, 64);
        }
        int lane = tid & 63, wv = tid >> 6;
        if (lane == 0) { s_red[wv][0] = acc_f; s_red[wv][1] = acc_b; s_red[wv][2] = acc_i; s_red[wv][3] = acc_p; }
        __syncthreads();
        if (tid == 0) {
            float f = 0, bb = 0, ii = 0, pp = 0;
            for (int w2 = 0; w2 < 4; ++w2) {
                f += s_red[w2][0]; bb += s_red[w2][1]; ii += s_red[w2][2]; pp += s_red[w2][3];
            }
            *reinterpret_cast<float4*>(partials + blk * 4) = make_float4(f, bb, ii, pp);
        }
    }

    grid.sync();

    // ---- phase E: block 0 -> reduce partials + forced-match delta correction + finalize ----
    if (blk == 0) {
        float acc_f = 0.f, acc_b = 0.f, acc_i = 0.f, acc_p = 0.f;
        for (int r = tid; r < NBLK; r += NTHR) {
            float4 v = *reinterpret_cast<const float4*>(partials + r * 4);
            acc_f += v.x; acc_b += v.y; acc_i += v.z; acc_p += v.w;
        }

        // forced corrections: wave w handles batch b = w (then b = w+4); lane = g
        for (int half = 0; half < 2; ++half) {
            int b = (tid >> 6) + half * 4;
            int g = tid & 63;
            int fa = forced_pair[b * G_N + g];
            bool win = (fa >= 0);
            for (int j = 0; j < 64; ++j) {
                int aj = __shfl(fa, j, 64);
                if (j > g && aj == fa) win = false;   // higher g forces same anchor -> it wins
            }
            if (win) {
                long ba = (long)b * A_N + fa;
                unsigned int ku = packed[ba];
                float xl = cls_logits[ba];
                bool pos_u = ku >= KEY_POS;
                bool neg_u = ku < KEY_NEG;
                // forced contribution (pos with gt g)
                float lb_f, li_f;
                pos_losses(anchors + fa * 5, gt_boxes + (b * G_N + g) * 5,
                           box_preds + ba * 6, int_logits + ba * C_INTN,
                           gt_int[b * G_N + g], lb_f, li_f);
                float df = focal_term(xl, true), db = lb_f, di = li_f, dp = 1.f;
                // subtract the unforced contribution phase D already counted
                if (pos_u) {
                    int g_u = 63 - (int)(ku & 63u);
                    float lb_u, li_u;
                    pos_losses(anchors + fa * 5, gt_boxes + (b * G_N + g_u) * 5,
                               box_preds + ba * 6, int_logits + ba * C_INTN,
                               gt_int[b * G_N + g_u], lb_u, li_u);
                    df -= focal_term(xl, true); db -= lb_u; di -= li_u; dp -= 1.f;
                } else if (neg_u) {
                    df -= focal_term(xl, false);
                }
                acc_f += df; acc_b += db; acc_i += di; acc_p += dp;
            }
        }

#pragma unroll
        for (int msk = 1; msk < 64; msk <<= 1) {
            acc_f += __shfl_xor(acc_f, msk, 64);
            acc_b += __shfl_xor(acc_b, msk, 64);
            acc_i += __shfl_xor(acc_i, msk, 64);
            acc_p += __shfl_xor(acc_p, msk, 64);
        }
        int lane = tid & 63, wv = tid >> 6;
        __syncthreads();   // s_red reuse after phase D
        if (lane == 0) { s_red[wv][0] = acc_f; s_red[wv][1] = acc_b; s_red[wv][2] = acc_i; s_red[wv][3] = acc_p; }
        __syncthreads();
        if (tid == 0) {
            float sf = 0, sb = 0, si = 0, sp = 0;
            for (int w2 = 0; w2 < 4; ++w2) {
                sf += s_red[w2][0]; sb += s_red[w2][1]; si += s_red[w2][2]; sp += s_red[w2][3];
            }
            float npv = fmaxf(sp, 1.0f);
            float lc = sf / npv, lb = sb / npv, li = si / npv;
            out[0] = lc + lb + 0.5f * li;   // CLS_W*lc + BOX_W*lb + INT_W*li
            out[1] = lc;
            out[2] = lb;
            out[3] = li;
            out[4] = sp;
        }
    }
}

// ---------- launch ----------

extern "C" void kernel_launch(void* const* d_in, const int* in_sizes, int n_in,
                              void* d_out, int out_size, void* d_ws, size_t ws_size,
                              hipStream_t stream) {
    const float* cls  = (const float*)d_in[0];
    const float* boxp = (const float*)d_in[1];
    const float* intl = (const float*)d_in[2];
    const float* anch = (const float*)d_in[3];
    const float* gtb  = (const float*)d_in[4];
    const int*   gti  = (const int*)d_in[5];
    const int*   gtv  = (const int*)d_in[6];
    float* out = (float*)d_out;

    char* ws = (char*)d_ws;
    const size_t MB = 1024ull * 1024ull;
    float4*       prep4       = (float4*)(ws);                   // A float4    = 2 MB
    float*        prepA       = (float*)(ws + 2 * MB);           // A f32       = 0.5 MB
    unsigned int* packed      = (unsigned int*)(ws + 3 * MB);    // B*A u32     = 4 MB
    int*          cell_list   = (int*)(ws + 7 * MB);             // 625*1024*4  = 2.5 MB
    int*          cell_count  = (int*)(ws + 10 * MB);            // 625*16 ints = 40 KB
    int*          forced_pair = (int*)(ws + 10 * MB + 64 * 1024);// 512 ints
    float*        partials    = (float*)(ws + 10 * MB + 128 * 1024); // 512*4 f32 = 8 KB

    void* args[] = {
        (void*)&anch, (void*)&gtb, (void*)&gtv, (void*)&gti,
        (void*)&cls, (void*)&boxp, (void*)&intl,
        (void*)&prep4, (void*)&prepA, (void*)&packed, (void*)&cell_count,
        (void*)&cell_list, (void*)&forced_pair, (void*)&partials, (void*)&out
    };
    hipLaunchCooperativeKernel((void*)k_fused, dim3(NBLK), dim3(NTHR), args, 0, stream);
}

// Round 6
// 52.960 us; speedup vs baseline: 5.4815x; 5.4815x over previous
//
#include <hip/hip_runtime.h>

#define A_N 131072
#define B_N 8
#define G_N 64
#define NGT (B_N * G_N)        // 512
#define C_INTN 8
#define EPSF 1e-6f

// GT spatial binning: cell 8 units; max center separation for IoU>0 is
// (w_a + w_g)/2 <= (6 + ~10)/2 < 8, so a 3x3 window suffices.
#define NCELL 25
#define NCC (NCELL * NCELL)    // 625
#define INV_CELL 0.125f

#define NBLK (A_N / 256)       // 512 blocks in k_main
#define CAND_K 256             // per-block force-candidate capacity (expected ~2)

// ---------- helpers ----------

__device__ __forceinline__ float focal_term(float xl, bool pos) {
    // alpha_t * softplus(z) * sigmoid(z)^2, z = pos ? -x : x
    float z = pos ? -xl : xl;
    float q = expf(-fabsf(z));
    float sp = fmaxf(z, 0.f) + log1pf(q);
    float r = 1.f / (1.f + q);
    float sg = (z >= 0.f) ? r : q * r;   // sigmoid(z)
    return (pos ? 0.25f : 0.75f) * sp * sg * sg;
}

// box smooth-L1 + intention CE for a positive anchor.
// ax..aang: raw anchor; q: raw gt row (x,y,w,l,ang); bp: box_preds row; il: int logits row
__device__ __forceinline__ void pos_losses(float ax, float ay, float aw, float al, float aang,
                                           const float* q, const float* __restrict__ bp,
                                           const float* __restrict__ il, int it,
                                           float& lb, float& li) {
    float awE = aw + EPSF, alE = al + EPSF;
    float hd = q[4] - aang;
    float bt[6];
    bt[0] = (q[0] - ax) / awE;
    bt[1] = (q[1] - ay) / alE;
    bt[2] = logf(q[2] / awE + EPSF);
    bt[3] = logf(q[3] / alE + EPSF);
    bt[4] = sinf(hd);
    bt[5] = cosf(hd);
    lb = 0.f;
#pragma unroll
    for (int k = 0; k < 6; ++k) {
        float d = fabsf(bp[k] - bt[k]);
        lb += (d < (1.0f / 9.0f)) ? (4.5f * d * d) : (d - 0.5f / 9.0f);
    }
    float lv[C_INTN];
#pragma unroll
    for (int c = 0; c < C_INTN; ++c) lv[c] = il[c];
    float mx = lv[0];
#pragma unroll
    for (int c = 1; c < C_INTN; ++c) mx = fmaxf(mx, lv[c]);
    float s = 0.f;
#pragma unroll
    for (int c = 0; c < C_INTN; ++c) s += expf(lv[c] - mx);
    float sel = lv[0];
#pragma unroll
    for (int c = 1; c < C_INTN; ++c) sel = (c == it) ? lv[c] : sel;  // static-index select
    li = (mx + logf(s)) - sel;
}

// build per-batch GT bitmask bins + raw GT cache in LDS (valid-masked)
__device__ __forceinline__ void build_gt_lds(const float* __restrict__ gt_boxes,
                                             const int* __restrict__ gt_valid,
                                             const int* __restrict__ gt_int,
                                             unsigned long long (*s_mask)[NCC],
                                             float (*s_gt)[5], int* s_gi,
                                             int tid, int nthr) {
    unsigned int* mask32 = (unsigned int*)&s_mask[0][0];
    for (int i = tid; i < B_N * NCC * 2; i += nthr) mask32[i] = 0u;
    __syncthreads();
    for (int i = tid; i < NGT; i += nthr) {
        const float* gb = gt_boxes + i * 5;
        float x = gb[0], y = gb[1];
        s_gt[i][0] = x; s_gt[i][1] = y;
        s_gt[i][2] = gb[2]; s_gt[i][3] = gb[3]; s_gt[i][4] = gb[4];
        s_gi[i] = gt_int[i];
        if (gt_valid[i] > 0) {
            int cx = min(max((int)(x * INV_CELL), 0), NCELL - 1);
            int cy = min(max((int)(y * INV_CELL), 0), NCELL - 1);
            int cell = cy * NCELL + cx;
            int b = i >> 6, g = i & 63;
            atomicOr(&mask32[(b * NCC + cell) * 2 + (g >> 5)], 1u << (g & 31));
        }
    }
    __syncthreads();
}

// ---------- kernel 1: fully-fused assign + loss, per-block partials + force candidates ----------

__global__ void __launch_bounds__(256, 2) k_main(
    const float* __restrict__ anchors, const float* __restrict__ gt_boxes,
    const int* __restrict__ gt_valid, const int* __restrict__ gt_int,
    const float* __restrict__ cls_logits, const float* __restrict__ box_preds,
    const float* __restrict__ int_logits,
    float* __restrict__ partials, unsigned long long* __restrict__ gcand,
    int* __restrict__ gcand_cnt)
{
    __shared__ unsigned long long s_mask[B_N][NCC];   // 40 KB
    __shared__ float s_gt[NGT][5];                    // 10 KB
    __shared__ int   s_gi[NGT];                       // 2 KB
    __shared__ float s_red[4][4];
    __shared__ int   s_cnt;

    const int tid = threadIdx.x;
    const int blk = blockIdx.x;
    if (tid == 0) s_cnt = 0;
    build_gt_lds(gt_boxes, gt_valid, gt_int, s_mask, s_gt, s_gi, tid, 256);

    // one anchor per thread
    const int a = blk * 256 + tid;
    const float* ap = anchors + a * 5;
    float ax = ap[0], ay = ap[1], aw = ap[2], alen = ap[3], aang = ap[4];
    float ax1 = ax - aw * 0.5f,  ax2 = ax + aw * 0.5f;
    float ay1 = ay - alen * 0.5f, ay2 = ay + alen * 0.5f;
    float asum = aw * alen + EPSF;
    int acx = min(max((int)(ax * INV_CELL), 0), NCELL - 1);
    int acy = min(max((int)(ay * INV_CELL), 0), NCELL - 1);
    int x0 = max(acx - 1, 0), x1i = min(acx + 1, NCELL - 1);
    int y0 = max(acy - 1, 0), y1i = min(acy + 1, NCELL - 1);

    float acc_f = 0.f, acc_b = 0.f, acc_i = 0.f, acc_p = 0.f;

    for (int b = 0; b < B_N; ++b) {
        float bi = 0.f; int bg = 0;
        for (int cy = y0; cy <= y1i; ++cy) {
            for (int cx = x0; cx <= x1i; ++cx) {
                unsigned long long m = s_mask[b][cy * NCELL + cx];
                while (m) {
                    int g = __builtin_ctzll(m); m &= m - 1;
                    const float* q = s_gt[b * G_N + g];
                    float gw = q[2], gl = q[3];
                    float iw = fminf(ax2, q[0] + gw * 0.5f) - fmaxf(ax1, q[0] - gw * 0.5f);
                    float ih = fminf(ay2, q[1] + gl * 0.5f) - fmaxf(ay1, q[1] - gl * 0.5f);
                    if (iw > 0.f && ih > 0.f) {
                        float inter = iw * ih;
                        float iou = inter * __builtin_amdgcn_rcpf(asum + gw * gl - inter);
                        if (iou > bi) { bi = iou; bg = g; }
                        if (iou >= 0.45f) {   // force-match candidate (rare: ~2/block)
                            int slot = atomicAdd(&s_cnt, 1);
                            if (slot < CAND_K) {
                                unsigned int fm = __float_as_uint(iou) | 0x80000000u; // fmono, iou>0
                                unsigned long long key =
                                    ((unsigned long long)fm << 32) |
                                    ((unsigned long long)((~(unsigned int)a) & 0x1FFFFu) << 9) |
                                    (unsigned long long)(b * G_N + g);
                                gcand[blk * CAND_K + slot] = key;
                            }
                        }
                    }
                }
            }
        }
        bool pos = bi >= 0.6f;
        bool neg = bi < 0.45f;
        float xl = cls_logits[b * A_N + a];
        if (pos | neg) acc_f += focal_term(xl, pos);
        if (pos) {
            acc_p += 1.f;
            int ba = b * A_N + a;
            float lb, li;
            pos_losses(ax, ay, aw, alen, aang, s_gt[b * G_N + bg],
                       box_preds + ba * 6, int_logits + ba * C_INTN,
                       s_gi[b * G_N + bg], lb, li);
            acc_b += lb; acc_i += li;
        }
    }

    // block reduce -> partials[blk] (always written; no init required)
#pragma unroll
    for (int msk = 1; msk < 64; msk <<= 1) {
        acc_f += __shfl_xor(acc_f, msk, 64);
        acc_b += __shfl_xor(acc_b, msk, 64);
        acc_i += __shfl_xor(acc_i, msk, 64);
        acc_p += __shfl_xor(acc_p, msk, 64);
    }
    int lane = tid & 63, wv = tid >> 6;
    if (lane == 0) { s_red[wv][0] = acc_f; s_red[wv][1] = acc_b; s_red[wv][2] = acc_i; s_red[wv][3] = acc_p; }
    __syncthreads();
    if (tid == 0) {
        float f = 0, bb = 0, ii = 0, pp = 0;
        for (int w2 = 0; w2 < 4; ++w2) {
            f += s_red[w2][0]; bb += s_red[w2][1]; ii += s_red[w2][2]; pp += s_red[w2][3];
        }
        *reinterpret_cast<float4*>(partials + blk * 4) = make_float4(f, bb, ii, pp);
        gcand_cnt[blk] = min(s_cnt, CAND_K);   // always written
    }
}

// ---------- kernel 2: reduce partials + force-match delta correction + finalize ----------

__global__ void __launch_bounds__(512) k_finale(
    const float* __restrict__ anchors, const float* __restrict__ gt_boxes,
    const int* __restrict__ gt_valid, const int* __restrict__ gt_int,
    const float* __restrict__ cls_logits, const float* __restrict__ box_preds,
    const float* __restrict__ int_logits,
    const float* __restrict__ partials, const unsigned long long* __restrict__ gcand,
    const int* __restrict__ gcand_cnt, float* __restrict__ out)
{
    __shared__ unsigned long long s_mask[B_N][NCC];   // 40 KB
    __shared__ float s_gt[NGT][5];
    __shared__ int   s_gi[NGT];
    __shared__ unsigned long long s_best[NGT];        // per-(b,g) argmax key
    __shared__ float s_red[8][4];

    const int tid = threadIdx.x;
    s_best[tid] = 0ull;
    build_gt_lds(gt_boxes, gt_valid, gt_int, s_mask, s_gt, s_gi, tid, 512);

    // base partial sums: thread t owns block t's partial (NBLK == 512)
    float4 v = *reinterpret_cast<const float4*>(partials + tid * 4);
    float acc_f = v.x, acc_b = v.y, acc_i = v.z, acc_p = v.w;

    // merge candidates: per-(b,g) max of (iou, ~a) via LDS CAS-max (order-independent)
    {
        int cnt = min(gcand_cnt[tid], CAND_K);
        for (int s = 0; s < cnt; ++s) {
            unsigned long long key = gcand[tid * CAND_K + s];
            int bg = (int)(key & 511ull);
            unsigned long long old = s_best[bg];
            while (key > old) {
                unsigned long long prev = atomicCAS(&s_best[bg], old, key);
                if (prev == old) break;
                old = prev;
            }
        }
    }
    __syncthreads();

    // winner per (b,g); resolve same-anchor collisions (max g wins); apply delta
    const int b = tid >> 6, g = tid & 63;
    unsigned long long key = s_best[tid];
    int fa = -1;
    if (key != 0ull) fa = (int)((~(unsigned int)(key >> 9)) & 0x1FFFFu);
    bool win = (fa >= 0);
    for (int j = 0; j < 64; ++j) {
        int aj = __shfl(fa, j, 64);
        if (j > g && aj == fa) win = false;   // higher g forcing same anchor wins
    }
    if (win) {
        const float* ap = anchors + fa * 5;
        float ax = ap[0], ay = ap[1], aw = ap[2], alen = ap[3], aang = ap[4];
        float ax1 = ax - aw * 0.5f,  ax2 = ax + aw * 0.5f;
        float ay1 = ay - alen * 0.5f, ay2 = ay + alen * 0.5f;
        float asum = aw * alen + EPSF;
        int acx = min(max((int)(ax * INV_CELL), 0), NCELL - 1);
        int acy = min(max((int)(ay * INV_CELL), 0), NCELL - 1);
        int x0 = max(acx - 1, 0), x1i = min(acx + 1, NCELL - 1);
        int y0 = max(acy - 1, 0), y1i = min(acy + 1, NCELL - 1);
        // recompute unforced label for (b, fa) — same iteration order as k_main
        float bi_u = 0.f; int bg_u = 0;
        for (int cy = y0; cy <= y1i; ++cy) {
            for (int cx = x0; cx <= x1i; ++cx) {
                unsigned long long m = s_mask[b][cy * NCELL + cx];
                while (m) {
                    int gg = __builtin_ctzll(m); m &= m - 1;
                    const float* q = s_gt[b * G_N + gg];
                    float gw = q[2], gl = q[3];
                    float iw = fminf(ax2, q[0] + gw * 0.5f) - fmaxf(ax1, q[0] - gw * 0.5f);
                    float ih = fminf(ay2, q[1] + gl * 0.5f) - fmaxf(ay1, q[1] - gl * 0.5f);
                    if (iw > 0.f && ih > 0.f) {
                        float inter = iw * ih;
                        float iou = inter * __builtin_amdgcn_rcpf(asum + gw * gl - inter);
                        if (iou > bi_u) { bi_u = iou; bg_u = gg; }
                    }
                }
            }
        }
        int ba = b * A_N + fa;
        float xl = cls_logits[ba];
        bool pos_u = bi_u >= 0.6f;
        bool neg_u = bi_u < 0.45f;
        // add forced contribution (pos with gt g)
        float lbf, lif;
        pos_losses(ax, ay, aw, alen, aang, s_gt[b * G_N + g],
                   box_preds + ba * 6, int_logits + ba * C_INTN,
                   s_gi[b * G_N + g], lbf, lif);
        acc_f += focal_term(xl, true); acc_b += lbf; acc_i += lif; acc_p += 1.f;
        // subtract the unforced contribution k_main already counted
        if (pos_u) {
            float lbu, liu;
            pos_losses(ax, ay, aw, alen, aang, s_gt[b * G_N + bg_u],
                       box_preds + ba * 6, int_logits + ba * C_INTN,
                       s_gi[b * G_N + bg_u], lbu, liu);
            acc_f -= focal_term(xl, true); acc_b -= lbu; acc_i -= liu; acc_p -= 1.f;
        } else if (neg_u) {
            acc_f -= focal_term(xl, false);
        }
    }

    // reduce over 512 threads (8 waves)
#pragma unroll
    for (int msk = 1; msk < 64; msk <<= 1) {
        acc_f += __shfl_xor(acc_f, msk, 64);
        acc_b += __shfl_xor(acc_b, msk, 64);
        acc_i += __shfl_xor(acc_i, msk, 64);
        acc_p += __shfl_xor(acc_p, msk, 64);
    }
    int lane = tid & 63, wv = tid >> 6;
    if (lane == 0) { s_red[wv][0] = acc_f; s_red[wv][1] = acc_b; s_red[wv][2] = acc_i; s_red[wv][3] = acc_p; }
    __syncthreads();
    if (tid == 0) {
        float sf = 0, sb = 0, si = 0, sp = 0;
        for (int w2 = 0; w2 < 8; ++w2) {
            sf += s_red[w2][0]; sb += s_red[w2][1]; si += s_red[w2][2]; sp += s_red[w2][3];
        }
        float npv = fmaxf(sp, 1.0f);
        float lc = sf / npv, lb = sb / npv, li = si / npv;
        out[0] = lc + lb + 0.5f * li;   // CLS_W*lc + BOX_W*lb + INT_W*li
        out[1] = lc;
        out[2] = lb;
        out[3] = li;
        out[4] = sp;
    }
}

// ---------- launch: exactly 2 dispatches, no workspace-state assumptions ----------

extern "C" void kernel_launch(void* const* d_in, const int* in_sizes, int n_in,
                              void* d_out, int out_size, void* d_ws, size_t ws_size,
                              hipStream_t stream) {
    const float* cls  = (const float*)d_in[0];
    const float* boxp = (const float*)d_in[1];
    const float* intl = (const float*)d_in[2];
    const float* anch = (const float*)d_in[3];
    const float* gtb  = (const float*)d_in[4];
    const int*   gti  = (const int*)d_in[5];
    const int*   gtv  = (const int*)d_in[6];
    float* out = (float*)d_out;

    char* ws = (char*)d_ws;
    unsigned long long* gcand = (unsigned long long*)(ws);              // 512*256*8 = 1 MB
    float* partials           = (float*)(ws + (1 << 20));               // 512*4 f32 = 8 KB
    int*   gcand_cnt          = (int*)(ws + (1 << 20) + (16 << 10));    // 512 ints

    k_main<<<NBLK, 256, 0, stream>>>(anch, gtb, gtv, gti, cls, boxp, intl,
                                     partials, gcand, gcand_cnt);

    k_finale<<<1, 512, 0, stream>>>(anch, gtb, gtv, gti, cls, boxp, intl,
                                    partials, gcand, gcand_cnt, out);
}